// Round 1
// baseline (38.765 us; speedup 1.0000x reference)
//
#include <hip/hip_runtime.h>
#include <cstdint>
#include <cstddef>

#define BB   32
#define AA   3
#define FF   76
#define NCH  85
#define NL   50
#define NCLS 80
#define CELLS (AA*FF*FF)              /* 17328 */
#define CPB  256
#define BPB  ((CELLS + CPB - 1)/CPB)  /* 68 */
#define NREC 16

__device__ __forceinline__ float slog(float x) {
    // torch-BCELoss-style clamped log
    return fmaxf(logf(fmaxf(x, 1e-43f)), -100.0f);
}

// ---------------- kernel 1: per-label records ----------------
__global__ void k_labels(const float* __restrict__ labels, float* __restrict__ recs) {
    int t = blockIdx.x * blockDim.x + threadIdx.x;
    if (t >= BB * NL) return;
    const float* L = labels + (size_t)t * 5;
    float c0 = L[0], x = L[1], y = L[2], w = L[3], h = L[4];
    bool  valid = (c0 + x + y + w + h) > 0.0f;
    float vf = valid ? 1.0f : 0.0f;

    float tx = x * 0.125f, ty = y * 0.125f;
    float tw = w * 0.125f, th = h * 0.125f;
    int   ti = (int)tx, tj = (int)ty;
    float twm = tw * vf, thm = th * vf;

    // ANCHORS / 8 (all exact in fp32)
    const float ag[9][2] = {
        {1.5f, 2.0f}, {2.375f, 4.5f}, {5.0f, 3.5f},
        {4.5f, 9.375f}, {9.5f, 6.875f}, {9.0f, 18.25f},
        {17.75f, 13.75f}, {24.0f, 30.375f}, {57.375f, 50.125f}
    };

    float at = twm * thm;
    float best = -1.0f; int bi = 0;
    for (int k = 0; k < 9; ++k) {
        float iw = fminf(twm, ag[k][0]);
        float ih = fminf(thm, ag[k][1]);
        float inter = (iw > 0.0f && ih > 0.0f) ? iw * ih : 0.0f;
        float iou = inter / (at + ag[k][0] * ag[k][1] - inter);
        if (iou > best) { best = iou; bi = k; }   // first-max wins, like jnp.argmax
    }
    int  bn    = bi % 3;
    bool write = (bi < 3) && valid;
    int  key   = write ? (bn * FF * FF + tj * FF + ti) : -1;

    float fx = tx - (float)ti;
    float fy = ty - (float)tj;
    float lw = logf(tw / ag[bn][0] + 1e-16f);
    float lh = logf(th / ag[bn][1] + 1e-16f);
    float sc = sqrtf(2.0f - tw * th * (1.0f / (float)(FF * FF)));
    int   cls = (int)c0;
    float tbx = tx * vf, tby = ty * vf;

    float* R = recs + (size_t)t * NREC;
    R[0]  = __int_as_float(key);
    R[1]  = fx;  R[2] = fy;  R[3] = lw;  R[4] = lh;  R[5] = sc;
    R[6]  = __int_as_float(cls);
    R[7]  = 0.0f;
    R[8]  = tbx - twm * 0.5f;   // truth left
    R[9]  = tbx + twm * 0.5f;   // truth right
    R[10] = tby - thm * 0.5f;   // truth bottom
    R[11] = tby + thm * 0.5f;   // truth top
    R[12] = twm * thm;          // truth area
    R[13] = 0.0f; R[14] = 0.0f; R[15] = 0.0f;
}

// ---------------- kernel 2: per-cell loss ----------------
__global__ void __launch_bounds__(CPB) k_main(const float* __restrict__ outp,
                                              const float* __restrict__ pred,
                                              const float* __restrict__ recs,
                                              float* __restrict__ partial) {
    __shared__ float R[NL * NREC];
    __shared__ float red[CPB];

    int bid = blockIdx.x;
    int b   = bid / BPB;
    int blk = bid % BPB;

    const float* src = recs + (size_t)b * NL * NREC;
    for (int i = threadIdx.x; i < NL * NREC; i += CPB) R[i] = src[i];
    __syncthreads();

    int   cell = blk * CPB + (int)threadIdx.x;
    float loss = 0.0f;

    if (cell < CELLS) {
        const float* pb = pred + ((size_t)b * CELLS + cell) * 4;
        float px = pb[0], py = pb[1], pw = pb[2], ph = pb[3];
        float plx = px - pw * 0.5f, prx = px + pw * 0.5f;
        float ply = py - ph * 0.5f, pry = py + ph * 0.5f;
        float ap  = pw * ph;

        float bestiou = 0.0f;
        int   mn = -1;
        #pragma unroll 5
        for (int n = 0; n < NL; ++n) {
            const float* r = &R[n * NREC];
            float lx = fmaxf(plx, r[8]);
            float rx = fminf(prx, r[9]);
            float ly = fmaxf(ply, r[10]);
            float ry = fminf(pry, r[11]);
            float w = rx - lx, h = ry - ly;
            float inter = (w > 0.0f && h > 0.0f) ? w * h : 0.0f;
            float iou = inter * __builtin_amdgcn_rcpf(ap + r[12] - inter);
            bestiou = fmaxf(bestiou, iou);
            if (__float_as_int(r[0]) == cell) mn = n;  // last write wins
        }

        const float* op = outp + ((size_t)b * CELLS + cell) * NCH;
        float p4 = op[4];
        if (mn >= 0) {
            const float* r = &R[mn * NREC];
            loss += -slog(p4);                       // obj, t=1
            float s = r[5], s2 = s * s;
            float t0 = r[1], t1 = r[2];
            float p0 = op[0], p1 = op[1];
            loss += -s2 * (t0 * slog(p0) + (1.0f - t0) * slog(1.0f - p0));
            loss += -s2 * (t1 * slog(p1) + (1.0f - t1) * slog(1.0f - p1));
            float d0 = op[2] * s - r[3] * s;
            float d1 = op[3] * s - r[4] * s;
            loss += 0.5f * (d0 * d0 + d1 * d1);
            int cls = __float_as_int(r[6]);
            for (int c = 0; c < NCLS; ++c) {
                float p = op[5 + c];
                loss += (c == cls) ? -slog(p) : -slog(1.0f - p);
            }
        } else if (!(bestiou > 0.7f)) {
            loss += -slog(1.0f - p4);                // obj, t=0, not ignored
        }
    }

    red[threadIdx.x] = loss;
    __syncthreads();
    for (int s = CPB / 2; s > 0; s >>= 1) {
        if ((int)threadIdx.x < s) red[threadIdx.x] += red[threadIdx.x + s];
        __syncthreads();
    }
    if (threadIdx.x == 0) partial[bid] = red[0];
}

// ---------------- kernel 3: deterministic final reduce ----------------
__global__ void k_reduce(const float* __restrict__ partial, float* __restrict__ out, int n) {
    __shared__ float red[256];
    float s = 0.0f;
    for (int i = threadIdx.x; i < n; i += 256) s += partial[i];
    red[threadIdx.x] = s;
    __syncthreads();
    for (int k = 128; k > 0; k >>= 1) {
        if ((int)threadIdx.x < k) red[threadIdx.x] += red[threadIdx.x + k];
        __syncthreads();
    }
    if (threadIdx.x == 0) out[0] = red[0];
}

extern "C" void kernel_launch(void* const* d_in, const int* in_sizes, int n_in,
                              void* d_out, int out_size, void* d_ws, size_t ws_size,
                              hipStream_t stream) {
    const float* outp   = (const float*)d_in[0];  // [32,3,76,76,85] probabilities
    const float* pred   = (const float*)d_in[1];  // [32,3,76,76,4] decoded boxes
    const float* labels = (const float*)d_in[2];  // [32,50,5]

    float* recs    = (float*)d_ws;                     // 32*50*16 floats = 102400 B
    float* partial = recs + (size_t)BB * NL * NREC;    // 2176 floats

    k_labels<<<(BB * NL + 255) / 256, 256, 0, stream>>>(labels, recs);
    k_main<<<BB * BPB, CPB, 0, stream>>>(outp, pred, recs, partial);
    k_reduce<<<1, 256, 0, stream>>>(partial, (float*)d_out, BB * BPB);
}